// Round 8
// baseline (239.059 us; speedup 1.0000x reference)
//
#include <hip/hip_runtime.h>

#define NUM_SEGS 1024
#define CHUNK_LOG 13
#define CHUNK (1 << CHUNK_LOG)   // 8192 elements per chunk
#define SUBCH 2                  // chunks per block (block span = 16384)
#define SUPER (CHUNK * SUBCH)
#define BLK 256                  // 4 waves/block; 1024 blocks -> 4 blocks/CU
#define NWAVE (BLK / 64)
#define NBATCH 16                // batches/thread (1 float4-triple each)
#define PDEPTH 6                 // asm pipeline depth (batches in flight)
#define SEGBLK 256

__device__ __forceinline__ float waveReduceSumF(float v) {
#pragma unroll
    for (int off = 32; off > 0; off >>= 1) v += __shfl_down(v, off, 64);
    return v;
}
__device__ __forceinline__ double waveReduceSumD(double v) {
#pragma unroll
    for (int off = 32; off > 0; off >>= 1) v += __shfl_down(v, off, 64);
    return v;
}
__device__ __forceinline__ unsigned waveReduceSumU(unsigned v) {
#pragma unroll
    for (int off = 32; off > 0; off >>= 1) v += __shfl_down(v, off, 64);
    return v;
}
__device__ __forceinline__ int waveReduceMaxI(int v) {
#pragma unroll
    for (int off = 32; off > 0; off >>= 1) {
        const int o = __shfl_down(v, off, 64);
        v = o > v ? o : v;
    }
    return v;
}

// ---------------- init: zero accumulators (ws is poisoned 0xAA every call) ---
__global__ void init_kernel(unsigned* __restrict__ seg_cnt,
                            float* __restrict__ csums, int nChunks,
                            unsigned* __restrict__ obs,
                            double* __restrict__ loss1,
                            double* __restrict__ loss2,
                            unsigned* __restrict__ done) {
    const int t = blockIdx.x * blockDim.x + threadIdx.x;
    if (t < NUM_SEGS) seg_cnt[t] = 0u;
    if (t < nChunks) csums[t] = 0.f;
    if (t == 0) { obs[0] = 0u; loss1[0] = 0.0; loss2[0] = 0.0; done[0] = 0u; }
}

// ---------------- pass 1: asm-forced depth-6 load pipeline -------------------
// Inline-asm global_load_dwordx4 (opaque to the scheduler, volatile-ordered)
// + hand-counted s_waitcnt vmcnt(N) (never 0 in steady state) + sched_barrier
// fences. Steady state: 18 loads (18KB) in flight per wave. vmcnt accounting
// is exact: the fast loop's ONLY vmem ops are these asm loads (LDS atomics
// and shuffles are lgkmcnt).
__global__ __launch_bounds__(BLK, 2) void pass1_kernel(
    const float* __restrict__ outs, const int* __restrict__ te,
    const int* __restrict__ tt, int N, int nChunks,
    float* __restrict__ csums, unsigned* __restrict__ seg_cnt,
    unsigned* __restrict__ obs, double* __restrict__ loss1) {
    __shared__ unsigned hist[NUM_SEGS];
    __shared__ float redF[NWAVE];
    __shared__ unsigned redU[NWAVE];

    for (int t = threadIdx.x; t < NUM_SEGS; t += BLK) hist[t] = 0u;
    __syncthreads();

    const int lane = threadIdx.x & 63;
    const int wid = threadIdx.x >> 6;
    const int superBase = blockIdx.x * SUPER;

    float sE[SUBCH] = {0.f, 0.f};  // batch b -> chunk b>>3 (compile-time)
    float sumOE = 0.f;
    unsigned cntE = 0u;

    if (superBase + SUPER <= N) {
        const int i0 = superBase + ((int)threadIdx.x << 2);
        float4 O[PDEPTH];
        int4 E[PDEPTH], S[PDEPTH];

#define ISSUE(b)                                                              \
    do {                                                                      \
        const float* _po = outs + (i0 + (b) * (BLK * 4));                     \
        const int* _pe = te + (i0 + (b) * (BLK * 4));                         \
        const int* _pt = tt + (i0 + (b) * (BLK * 4));                         \
        asm volatile("global_load_dwordx4 %0, %1, off"                        \
                     : "=&v"(O[(b) % PDEPTH]) : "v"(_po));                    \
        asm volatile("global_load_dwordx4 %0, %1, off"                        \
                     : "=&v"(E[(b) % PDEPTH]) : "v"(_pe));                    \
        asm volatile("global_load_dwordx4 %0, %1, off"                        \
                     : "=&v"(S[(b) % PDEPTH]) : "v"(_pt));                    \
    } while (0)

#define CONSUME(b)                                                            \
    do {                                                                      \
        const float4 o = O[(b) % PDEPTH];                                     \
        const int4 ev = E[(b) % PDEPTH];                                      \
        const int4 sv = S[(b) % PDEPTH];                                      \
        sE[(b) >> 3] += (__expf(o.x) + __expf(o.y)) +                         \
                        (__expf(o.z) + __expf(o.w));                          \
        const int s0 = sv.x < 0 ? -sv.x : sv.x;                               \
        const int s1 = sv.y < 0 ? -sv.y : sv.y;                               \
        const int s2 = sv.z < 0 ? -sv.z : sv.z;                               \
        const int s3 = sv.w < 0 ? -sv.w : sv.w;                               \
        if (ev.x > 0) { cntE++; sumOE += o.x; atomicAdd(&hist[s0], 1u); }     \
        if (ev.y > 0) { cntE++; sumOE += o.y; atomicAdd(&hist[s1], 1u); }     \
        if (ev.z > 0) { cntE++; sumOE += o.z; atomicAdd(&hist[s2], 1u); }     \
        if (ev.w > 0) { cntE++; sumOE += o.w; atomicAdd(&hist[s3], 1u); }     \
    } while (0)

// STEP: wait batch b's 3 loads (counted, never draining the pipe), fence,
// consume, fence (so consume reads can't sink past the slot re-issue), issue
// batch b+PDEPTH into the freed slot.
#define STEP(b, wc)                                                           \
    do {                                                                      \
        asm volatile("s_waitcnt vmcnt(" #wc ")");                             \
        __builtin_amdgcn_sched_barrier(0);                                    \
        CONSUME(b);                                                           \
        __builtin_amdgcn_sched_barrier(0);                                    \
        if ((b) + PDEPTH < NBATCH) ISSUE((b) + PDEPTH);                       \
    } while (0)

        // prologue: fill the pipeline (6 batches = 18 loads in flight)
        ISSUE(0); ISSUE(1); ISSUE(2); ISSUE(3); ISSUE(4); ISSUE(5);
        // steady state: outstanding 18 -> wait 15 retires exactly batch b
        STEP(0, 15);  STEP(1, 15);  STEP(2, 15);  STEP(3, 15);
        STEP(4, 15);  STEP(5, 15);  STEP(6, 15);  STEP(7, 15);
        STEP(8, 15);  STEP(9, 15);  STEP(10, 15);
        // drain
        STEP(11, 12); STEP(12, 9);  STEP(13, 6);  STEP(14, 3);  STEP(15, 0);

#undef STEP
#undef CONSUME
#undef ISSUE

        // per-wave chunk-sum flush: one float atomic per (wave, chunk)
        const int c0 = superBase >> CHUNK_LOG;
#pragma unroll
        for (int k = 0; k < SUBCH; ++k) {
            const float w = waveReduceSumF(sE[k]);
            if (lane == 0) atomicAdd(&csums[c0 + k], w);
        }
    } else {
        // tail path (not hit for N = 16M)
        for (int k = 0; k < SUBCH; ++k) {
            const int cbase = superBase + k * CHUNK;
            if (cbase >= N) break;
            const int end = (cbase + CHUNK < N) ? cbase + CHUNK : N;
            float s = 0.f;
            for (int i = cbase + (int)threadIdx.x; i < end; i += BLK) {
                const float o = outs[i];
                const int e = te[i];
                int sg = tt[i]; sg = sg < 0 ? -sg : sg;
                s += __expf(o);
                if (e > 0) { cntE++; sumOE += o; atomicAdd(&hist[sg], 1u); }
            }
            const float w = waveReduceSumF(s);
            if (lane == 0 && w != 0.f) atomicAdd(&csums[cbase >> CHUNK_LOG], w);
        }
    }

    __syncthreads();  // the only mid-kernel block barrier: hist complete

    for (int t = threadIdx.x; t < NUM_SEGS; t += BLK) {
        const unsigned h = hist[t];
        if (h) atomicAdd(&seg_cnt[t], h);
    }

    // block-reduce E stats
    const float wOE = waveReduceSumF(sumOE);
    const unsigned wC = waveReduceSumU(cntE);
    if (lane == 0) { redF[wid] = wOE; redU[wid] = wC; }
    __syncthreads();
    if (threadIdx.x == 0) {
        float oe = 0.f; unsigned c = 0u;
#pragma unroll
        for (int j = 0; j < NWAVE; ++j) { oe += redF[j]; c += redU[j]; }
        atomicAdd(loss1, (double)oe);
        atomicAdd(obs, c);
    }
}

// ---------------- pass 2 (fused): backward last-idx search + prefix + finalize
__global__ __launch_bounds__(SEGBLK) void seg_final_kernel(
    const float* __restrict__ outs, const int* __restrict__ tt,
    const float* __restrict__ csums, const unsigned* __restrict__ seg_cnt,
    const double* __restrict__ loss1, double* __restrict__ loss2,
    const unsigned* __restrict__ obs, unsigned* __restrict__ done,
    float* __restrict__ out, int N, int nChunks) {
    __shared__ double redD[SEGBLK / 64];
    __shared__ float redF[SEGBLK / 64];
    __shared__ int redI[SEGBLK / 64];
    __shared__ int s_li;

    const int t = blockIdx.x;
    const unsigned cnt = seg_cnt[t];
    const int lane = threadIdx.x & 63, wid = threadIdx.x >> 6;

    if (cnt != 0u) {  // cnt==0 segments contribute 0
        // ---- backward search for the last occurrence of segment t ----
        int c = nChunks - 1;
        int LI = -1;
        for (;;) {
            const int base = c << CHUNK_LOG;
            const int end = (base + CHUNK < N) ? base + CHUNK : N;
            const int span = end - base;
            const int qspan = span & ~3;  // int4-aligned portion
            int li = -1;
            for (int i = base + ((int)threadIdx.x << 2); i < base + qspan;
                 i += SEGBLK * 4) {
                const int4 sv = *reinterpret_cast<const int4*>(tt + i);
                const int s0 = sv.x < 0 ? -sv.x : sv.x;
                const int s1 = sv.y < 0 ? -sv.y : sv.y;
                const int s2 = sv.z < 0 ? -sv.z : sv.z;
                const int s3 = sv.w < 0 ? -sv.w : sv.w;
                if (s3 == t) li = i + 3;
                else if (s2 == t) li = i + 2;
                else if (s1 == t) li = i + 1;
                else if (s0 == t) li = i;
                // ascending i => later assignment always larger
            }
            for (int i = base + qspan + (int)threadIdx.x; i < end; i += SEGBLK) {
                int s = tt[i]; s = s < 0 ? -s : s;
                if (s == t && i > li) li = i;
            }
            li = waveReduceMaxI(li);
            if (lane == 0) redI[wid] = li;
            __syncthreads();
            if (threadIdx.x == 0) {
                int m = redI[0];
#pragma unroll
                for (int j = 1; j < SEGBLK / 64; ++j) m = redI[j] > m ? redI[j] : m;
                s_li = m;
            }
            __syncthreads();
            LI = s_li;
            if (LI >= 0 || --c < 0) break;
        }

        if (LI >= 0) {
            // fp64 exclusive prefix of chunk sums [0, c)
            double p = 0.0;
            for (int j = threadIdx.x; j < c; j += SEGBLK) p += (double)csums[j];
            p = waveReduceSumD(p);
            if (lane == 0) redD[wid] = p;

            // fp32 in-chunk exp-sum up to and including LI
            const int base = c << CHUNK_LOG;
            float fs = 0.f;
            for (int i = base + (int)threadIdx.x; i <= LI; i += SEGBLK)
                fs += __expf(outs[i]);
            fs = waveReduceSumF(fs);
            if (lane == 0) redF[wid] = fs;
            __syncthreads();
            if (threadIdx.x == 0) {
                double pre = 0.0;
                float fsum = 0.f;
#pragma unroll
                for (int j = 0; j < SEGBLK / 64; ++j) { pre += redD[j]; fsum += redF[j]; }
                double sm = log(pre + (double)fsum);  // monotone cumsum => max at LI
                if (sm < 0.0) sm = 0.0;               // jnp.maximum(..., 0.0)
                atomicAdd(loss2, sm * (double)cnt);
            }
        }
    }

    // done-ticket: last block finalizes (no separate final kernel)
    if (threadIdx.x == 0) {
        __threadfence();
        const unsigned d = atomicAdd(done, 1u);
        if (d == (unsigned)(gridDim.x - 1)) {
            const double l2 = atomicAdd(loss2, 0.0);            // atomic read
            const double l1 = *(volatile const double*)loss1;   // prior dispatch
            const unsigned o = *(volatile const unsigned*)obs;
            out[0] = (float)((l2 - l1) / (double)o);
        }
    }
}

extern "C" void kernel_launch(void* const* d_in, const int* in_sizes, int n_in,
                              void* d_out, int out_size, void* d_ws, size_t ws_size,
                              hipStream_t stream) {
    const float* outs = (const float*)d_in[0];
    const int* te = (const int*)d_in[1];
    const int* tt = (const int*)d_in[2];
    const int N = in_sizes[0];
    float* out = (float*)d_out;

    const int nChunks = (N + CHUNK - 1) / CHUNK;

    char* ws = (char*)d_ws;
    double* d_loss1 = (double*)ws;                        // 1 double
    double* d_loss2 = d_loss1 + 1;                        // 1 double
    float* d_csums = (float*)(ws + 16);                   // nChunks floats
    unsigned* d_segcnt = (unsigned*)(d_csums + nChunks);  // NUM_SEGS u32
    unsigned* d_obs = d_segcnt + NUM_SEGS;
    unsigned* d_done = d_obs + 1;

    const int initThreads = (nChunks > NUM_SEGS ? nChunks : NUM_SEGS);
    init_kernel<<<(initThreads + 255) / 256, 256, 0, stream>>>(
        d_segcnt, d_csums, nChunks, d_obs, d_loss1, d_loss2, d_done);
    const int nSuper = (N + SUPER - 1) / SUPER;
    pass1_kernel<<<nSuper, BLK, 0, stream>>>(outs, te, tt, N, nChunks, d_csums,
                                             d_segcnt, d_obs, d_loss1);
    seg_final_kernel<<<NUM_SEGS, SEGBLK, 0, stream>>>(
        outs, tt, d_csums, d_segcnt, d_loss1, d_loss2, d_obs, d_done, out, N,
        nChunks);
}

// Round 10
// 213.424 us; speedup vs baseline: 1.1201x; 1.1201x over previous
//
#include <hip/hip_runtime.h>

#define NUM_SEGS 1024
#define CHUNK_LOG 13
#define CHUNK (1 << CHUNK_LOG)   // 8192 elements per chunk
#define SUBCH 4                  // chunks per block (superchunk = 32768)
#define SUPER (CHUNK * SUBCH)
#define BLK 512                  // 8 waves/block (r7's proven pass1 geometry)
#define NWAVE (BLK / 64)
#define NBATCH 16                // batches/thread (1 float4-triple each)
#define PDEPTH 6                 // software-pipeline depth (r7's proven config)
#define SEGBLK 256
#define SEGWAVES (SEGBLK / 64)

__device__ __forceinline__ float waveReduceSumF(float v) {
#pragma unroll
    for (int off = 32; off > 0; off >>= 1) v += __shfl_down(v, off, 64);
    return v;
}
__device__ __forceinline__ double waveReduceSumD(double v) {
#pragma unroll
    for (int off = 32; off > 0; off >>= 1) v += __shfl_down(v, off, 64);
    return v;
}
__device__ __forceinline__ unsigned waveReduceSumU(unsigned v) {
#pragma unroll
    for (int off = 32; off > 0; off >>= 1) v += __shfl_down(v, off, 64);
    return v;
}
__device__ __forceinline__ int waveReduceMaxI(int v) {
#pragma unroll
    for (int off = 32; off > 0; off >>= 1) {
        const int o = __shfl_down(v, off, 64);
        v = o > v ? o : v;
    }
    return v;
}

// ---------------- pass 1: r7's 63us streaming body, all-plain-store outputs --
// No pre-zeroed workspace needed: every ws location is written (plain stores)
// before seg_final reads it. Outputs per block bid:
//   csums[c0..c0+3]          : block-reduced chunk exp-sums (block owns chunks)
//   hist_part[bid][0..1023]  : u16 per-segment E-counts (max 32768 fits u16)
//   e1part[bid], obspart[bid]: block E-stat partials
__global__ __launch_bounds__(BLK, 2) void pass1_kernel(
    const float* __restrict__ outs, const int* __restrict__ te,
    const int* __restrict__ tt, int N, int nChunks,
    float* __restrict__ csums, unsigned short* __restrict__ hist_part,
    float* __restrict__ e1part, unsigned* __restrict__ obspart) {
    __shared__ unsigned hist[NUM_SEGS];
    __shared__ float redC[SUBCH][NWAVE];
    __shared__ float redF[NWAVE];
    __shared__ unsigned redU[NWAVE];

    for (int t = threadIdx.x; t < NUM_SEGS; t += BLK) hist[t] = 0u;
    __syncthreads();

    const int lane = threadIdx.x & 63;
    const int wid = threadIdx.x >> 6;
    const int bid = (int)blockIdx.x;
    const int superBase = bid * SUPER;

    float sE[SUBCH] = {0.f, 0.f, 0.f, 0.f};  // batch b -> chunk b>>2 (static)
    float sumOE = 0.f;
    unsigned cntE = 0u;

    if (superBase + SUPER <= N) {
        const int i0 = superBase + ((int)threadIdx.x << 2);
        float4 O[PDEPTH];
        int4 E[PDEPTH], S[PDEPTH];

#define LOADB(b, sl)                                                        \
    do {                                                                    \
        const int _i = i0 + (b) * (BLK * 4);                                \
        O[sl] = *reinterpret_cast<const float4*>(outs + _i);                \
        E[sl] = *reinterpret_cast<const int4*>(te + _i);                    \
        S[sl] = *reinterpret_cast<const int4*>(tt + _i);                    \
    } while (0)

        // prologue: fill the pipeline
#pragma unroll
        for (int b = 0; b < PDEPTH; ++b) LOADB(b, b);

#pragma unroll
        for (int b = 0; b < NBATCH; ++b) {
            if (b + PDEPTH < NBATCH) LOADB(b + PDEPTH, (b + PDEPTH) % PDEPTH);
            __builtin_amdgcn_sched_barrier(0);  // pin issue above consume
            {
                const int sl = b % PDEPTH;  // compile-time (unrolled)
                const float4 o = O[sl];
                const int4 ev = E[sl];
                const int4 sv = S[sl];
                sE[b >> 2] += (__expf(o.x) + __expf(o.y)) +
                              (__expf(o.z) + __expf(o.w));
                const int s0 = sv.x < 0 ? -sv.x : sv.x;
                const int s1 = sv.y < 0 ? -sv.y : sv.y;
                const int s2 = sv.z < 0 ? -sv.z : sv.z;
                const int s3 = sv.w < 0 ? -sv.w : sv.w;
                if (ev.x > 0) { cntE++; sumOE += o.x; atomicAdd(&hist[s0], 1u); }
                if (ev.y > 0) { cntE++; sumOE += o.y; atomicAdd(&hist[s1], 1u); }
                if (ev.z > 0) { cntE++; sumOE += o.z; atomicAdd(&hist[s2], 1u); }
                if (ev.w > 0) { cntE++; sumOE += o.w; atomicAdd(&hist[s3], 1u); }
            }
        }
#undef LOADB

        // per-chunk wave partials -> LDS
#pragma unroll
        for (int k = 0; k < SUBCH; ++k) {
            const float w = waveReduceSumF(sE[k]);
            if (lane == 0) redC[k][wid] = w;
        }
    } else {
        // tail path (not hit for N = 16M); block still owns its chunks
        if (lane == 0) {
#pragma unroll
            for (int k = 0; k < SUBCH; ++k) redC[k][wid] = 0.f;
        }
        for (int k = 0; k < SUBCH; ++k) {
            const int cbase = superBase + k * CHUNK;
            if (cbase >= N) break;
            const int end = (cbase + CHUNK < N) ? cbase + CHUNK : N;
            float s = 0.f;
            for (int i = cbase + (int)threadIdx.x; i < end; i += BLK) {
                const float o = outs[i];
                const int e = te[i];
                int sg = tt[i]; sg = sg < 0 ? -sg : sg;
                s += __expf(o);
                if (e > 0) { cntE++; sumOE += o; atomicAdd(&hist[sg], 1u); }
            }
            const float w = waveReduceSumF(s);
            if (lane == 0) redC[k][wid] = w;
        }
    }

    // E-stat wave partials
    {
        const float wOE = waveReduceSumF(sumOE);
        const unsigned wC = waveReduceSumU(cntE);
        if (lane == 0) { redF[wid] = wOE; redU[wid] = wC; }
    }

    __syncthreads();  // hist + redC/redF/redU complete

    // hist -> per-block u16 partials (plain coalesced stores, no atomics)
    for (int t = threadIdx.x; t < NUM_SEGS; t += BLK)
        hist_part[(size_t)bid * NUM_SEGS + t] = (unsigned short)hist[t];

    if (threadIdx.x == 0) {
        const int c0 = superBase >> CHUNK_LOG;
#pragma unroll
        for (int k = 0; k < SUBCH; ++k) {
            const int cbase = superBase + k * CHUNK;
            if (cbase < N) {
                float cs = 0.f;
#pragma unroll
                for (int j = 0; j < NWAVE; ++j) cs += redC[k][j];
                csums[c0 + k] = cs;
            }
        }
        float oe = 0.f; unsigned c = 0u;
#pragma unroll
        for (int j = 0; j < NWAVE; ++j) { oe += redF[j]; c += redU[j]; }
        e1part[bid] = oe;
        obspart[bid] = c;
    }
}

// ---------------- pass 2: per-segment work + direct fp32 accumulation to out -
// Block t: cnt = column-sum of hist_part; backward last-idx search (random
// data: hit in the last chunk, L2-hot); fp64 prefix over csums[0..c); fp32
// in-chunk exp-sum; atomicAdd(out, sm*cnt/Obs). Block 0 adds -loss1/Obs.
// out is pre-zeroed by the harness memset before launch.
__global__ __launch_bounds__(SEGBLK) void seg_final_kernel(
    const float* __restrict__ outs, const int* __restrict__ tt,
    const float* __restrict__ csums, const unsigned short* __restrict__ hist_part,
    const float* __restrict__ e1part, const unsigned* __restrict__ obspart,
    float* __restrict__ out, int N, int nChunks, int nSuper) {
    __shared__ double redD[SEGWAVES];
    __shared__ float redF[SEGWAVES];
    __shared__ int redI[SEGWAVES];
    __shared__ unsigned redObs[SEGWAVES];
    __shared__ unsigned redCnt[SEGWAVES];
    __shared__ int s_li;
    __shared__ unsigned s_cnt;

    const int t = (int)blockIdx.x;
    const int tid = (int)threadIdx.x;
    const int lane = tid & 63, wid = tid >> 6;

    // Obs partial-sum (kept in redObs; only tid 0 consumes it later)
    {
        unsigned ob = 0u;
        for (int b = tid; b < nSuper; b += SEGBLK) ob += obspart[b];
        ob = waveReduceSumU(ob);
        if (lane == 0) redObs[wid] = ob;
    }

    // block 0: the -loss1/Obs term
    if (t == 0) {
        double p = 0.0;
        for (int b = tid; b < nSuper; b += SEGBLK) p += (double)e1part[b];
        p = waveReduceSumD(p);
        if (lane == 0) redD[wid] = p;
        __syncthreads();
        if (tid == 0) {
            double L1 = 0.0, Obs = 0.0;
#pragma unroll
            for (int j = 0; j < SEGWAVES; ++j) {
                L1 += redD[j];
                Obs += (double)redObs[j];
            }
            atomicAdd(out, (float)(-L1 / Obs));
        }
        __syncthreads();  // redD reused below
    }

    // cnt for this segment: column sum of u16 partials
    {
        unsigned c = 0u;
        for (int b = tid; b < nSuper; b += SEGBLK)
            c += (unsigned)hist_part[(size_t)b * NUM_SEGS + t];
        c = waveReduceSumU(c);
        if (lane == 0) redCnt[wid] = c;
    }
    __syncthreads();
    if (tid == 0) {
        unsigned c = 0u;
#pragma unroll
        for (int j = 0; j < SEGWAVES; ++j) c += redCnt[j];
        s_cnt = c;
    }
    __syncthreads();
    const unsigned cnt = s_cnt;
    if (cnt == 0u) return;  // empty segment contributes 0

    // ---- backward search for the last occurrence of segment t ----
    int c = nChunks - 1;
    int LI = -1;
    for (;;) {
        const int base = c << CHUNK_LOG;
        const int end = (base + CHUNK < N) ? base + CHUNK : N;
        const int span = end - base;
        const int qspan = span & ~3;  // int4-aligned portion
        int li = -1;
        for (int i = base + (tid << 2); i < base + qspan; i += SEGBLK * 4) {
            const int4 sv = *reinterpret_cast<const int4*>(tt + i);
            const int s0 = sv.x < 0 ? -sv.x : sv.x;
            const int s1 = sv.y < 0 ? -sv.y : sv.y;
            const int s2 = sv.z < 0 ? -sv.z : sv.z;
            const int s3 = sv.w < 0 ? -sv.w : sv.w;
            if (s3 == t) li = i + 3;
            else if (s2 == t) li = i + 2;
            else if (s1 == t) li = i + 1;
            else if (s0 == t) li = i;
            // ascending i => later assignment always larger
        }
        for (int i = base + qspan + tid; i < end; i += SEGBLK) {
            int s = tt[i]; s = s < 0 ? -s : s;
            if (s == t && i > li) li = i;
        }
        li = waveReduceMaxI(li);
        if (lane == 0) redI[wid] = li;
        __syncthreads();
        if (tid == 0) {
            int m = redI[0];
#pragma unroll
            for (int j = 1; j < SEGWAVES; ++j) m = redI[j] > m ? redI[j] : m;
            s_li = m;
        }
        __syncthreads();
        LI = s_li;
        if (LI >= 0 || --c < 0) break;
    }
    if (LI < 0) return;

    // fp64 exclusive prefix of chunk sums [0, c)
    {
        double p = 0.0;
        for (int j = tid; j < c; j += SEGBLK) p += (double)csums[j];
        p = waveReduceSumD(p);
        if (lane == 0) redD[wid] = p;
    }

    // fp32 in-chunk exp-sum up to and including LI
    {
        const int base = c << CHUNK_LOG;
        float fs = 0.f;
        for (int i = base + tid; i <= LI; i += SEGBLK) fs += __expf(outs[i]);
        fs = waveReduceSumF(fs);
        if (lane == 0) redF[wid] = fs;
    }
    __syncthreads();
    if (tid == 0) {
        double pre = 0.0, Obs = 0.0;
        float fsum = 0.f;
#pragma unroll
        for (int j = 0; j < SEGWAVES; ++j) {
            pre += redD[j];
            fsum += redF[j];
            Obs += (double)redObs[j];
        }
        double sm = log(pre + (double)fsum);  // monotone cumsum => max at LI
        if (sm < 0.0) sm = 0.0;               // jnp.maximum(..., 0.0)
        atomicAdd(out, (float)(sm * (double)cnt / Obs));
    }
}

extern "C" void kernel_launch(void* const* d_in, const int* in_sizes, int n_in,
                              void* d_out, int out_size, void* d_ws, size_t ws_size,
                              hipStream_t stream) {
    const float* outs = (const float*)d_in[0];
    const int* te = (const int*)d_in[1];
    const int* tt = (const int*)d_in[2];
    const int N = in_sizes[0];
    float* out = (float*)d_out;

    const int nChunks = (N + CHUNK - 1) / CHUNK;
    const int nSuper = (N + SUPER - 1) / SUPER;

    // workspace layout: everything is written by pass1 before seg_final reads
    // it -- no initialization dispatch, no poisoned-state hazard.
    char* ws = (char*)d_ws;
    float* d_csums = (float*)ws;                                   // nChunks f32
    unsigned short* d_histp = (unsigned short*)(d_csums + nChunks);  // nSuper*1024 u16
    float* d_e1 = (float*)(d_histp + (size_t)nSuper * NUM_SEGS);   // nSuper f32
    unsigned* d_obsp = (unsigned*)(d_e1 + nSuper);                 // nSuper u32

    pass1_kernel<<<nSuper, BLK, 0, stream>>>(outs, te, tt, N, nChunks, d_csums,
                                             d_histp, d_e1, d_obsp);
    seg_final_kernel<<<NUM_SEGS, SEGBLK, 0, stream>>>(
        outs, tt, d_csums, d_histp, d_e1, d_obsp, out, N, nChunks, nSuper);
}

// Round 11
// 208.387 us; speedup vs baseline: 1.1472x; 1.0242x over previous
//
#include <hip/hip_runtime.h>

#define NUM_SEGS 1024
#define CHUNK_LOG 13
#define CHUNK (1 << CHUNK_LOG)   // 8192 elements per chunk
#define SUBCH 4                  // chunks per block (superchunk = 32768)
#define SUPER (CHUNK * SUBCH)
#define BLK 1024                 // 16 waves/block; grid 512 -> 2 blocks/CU = 32 waves/CU
#define NWAVE (BLK / 64)
#define NBATCH 8                 // batches/thread (1 float4-triple each)
#define PDEPTH 4                 // software-pipeline depth (12 loads in flight)
#define SEGBLK 256
#define SEGWAVES (SEGBLK / 64)

__device__ __forceinline__ float waveReduceSumF(float v) {
#pragma unroll
    for (int off = 32; off > 0; off >>= 1) v += __shfl_down(v, off, 64);
    return v;
}
__device__ __forceinline__ double waveReduceSumD(double v) {
#pragma unroll
    for (int off = 32; off > 0; off >>= 1) v += __shfl_down(v, off, 64);
    return v;
}
__device__ __forceinline__ unsigned waveReduceSumU(unsigned v) {
#pragma unroll
    for (int off = 32; off > 0; off >>= 1) v += __shfl_down(v, off, 64);
    return v;
}
__device__ __forceinline__ int waveReduceMaxI(int v) {
#pragma unroll
    for (int off = 32; off > 0; off >>= 1) {
        const int o = __shfl_down(v, off, 64);
        v = o > v ? o : v;
    }
    return v;
}

// ---------------- pass 1: r10's pipelined body at 32 waves/CU ----------------
// Same PDEPTH rotating-buffer + sched_barrier pipeline (the only mechanism
// that ever raised per-wave MLP), now at 2x resident waves: BLK=1024, 2
// blocks/CU -> 32 waves/CU. All outputs plain stores (no init dispatch).
//   csums[c0..c0+3]          : block-reduced chunk exp-sums (block owns chunks)
//   hist_part[bid][0..1023]  : u16 per-segment E-counts (max 32768 fits u16)
//   e1part[bid], obspart[bid]: block E-stat partials
__global__ __launch_bounds__(BLK, 8) void pass1_kernel(
    const float* __restrict__ outs, const int* __restrict__ te,
    const int* __restrict__ tt, int N, int nChunks,
    float* __restrict__ csums, unsigned short* __restrict__ hist_part,
    float* __restrict__ e1part, unsigned* __restrict__ obspart) {
    __shared__ unsigned hist[NUM_SEGS];
    __shared__ float redC[SUBCH][NWAVE];
    __shared__ float redF[NWAVE];
    __shared__ unsigned redU[NWAVE];

    for (int t = threadIdx.x; t < NUM_SEGS; t += BLK) hist[t] = 0u;
    __syncthreads();

    const int lane = threadIdx.x & 63;
    const int wid = threadIdx.x >> 6;
    const int bid = (int)blockIdx.x;
    const int superBase = bid * SUPER;

    float sE[SUBCH] = {0.f, 0.f, 0.f, 0.f};  // batch b -> chunk b>>1 (static)
    float sumOE = 0.f;
    unsigned cntE = 0u;

    if (superBase + SUPER <= N) {
        const int i0 = superBase + ((int)threadIdx.x << 2);
        float4 O[PDEPTH];
        int4 E[PDEPTH], S[PDEPTH];

#define LOADB(b, sl)                                                        \
    do {                                                                    \
        const int _i = i0 + (b) * (BLK * 4);                                \
        O[sl] = *reinterpret_cast<const float4*>(outs + _i);                \
        E[sl] = *reinterpret_cast<const int4*>(te + _i);                    \
        S[sl] = *reinterpret_cast<const int4*>(tt + _i);                    \
    } while (0)

        // prologue: fill the pipeline (12 loads in flight)
#pragma unroll
        for (int b = 0; b < PDEPTH; ++b) LOADB(b, b);

#pragma unroll
        for (int b = 0; b < NBATCH; ++b) {
            if (b + PDEPTH < NBATCH) LOADB(b + PDEPTH, (b + PDEPTH) % PDEPTH);
            __builtin_amdgcn_sched_barrier(0);  // pin issue above consume
            {
                const int sl = b % PDEPTH;  // compile-time (unrolled)
                const float4 o = O[sl];
                const int4 ev = E[sl];
                const int4 sv = S[sl];
                sE[b >> 1] += (__expf(o.x) + __expf(o.y)) +
                              (__expf(o.z) + __expf(o.w));
                const int s0 = sv.x < 0 ? -sv.x : sv.x;
                const int s1 = sv.y < 0 ? -sv.y : sv.y;
                const int s2 = sv.z < 0 ? -sv.z : sv.z;
                const int s3 = sv.w < 0 ? -sv.w : sv.w;
                if (ev.x > 0) { cntE++; sumOE += o.x; atomicAdd(&hist[s0], 1u); }
                if (ev.y > 0) { cntE++; sumOE += o.y; atomicAdd(&hist[s1], 1u); }
                if (ev.z > 0) { cntE++; sumOE += o.z; atomicAdd(&hist[s2], 1u); }
                if (ev.w > 0) { cntE++; sumOE += o.w; atomicAdd(&hist[s3], 1u); }
            }
        }
#undef LOADB

        // per-chunk wave partials -> LDS
#pragma unroll
        for (int k = 0; k < SUBCH; ++k) {
            const float w = waveReduceSumF(sE[k]);
            if (lane == 0) redC[k][wid] = w;
        }
    } else {
        // tail path (not hit for N = 16M); block still owns its chunks
        if (lane == 0) {
#pragma unroll
            for (int k = 0; k < SUBCH; ++k) redC[k][wid] = 0.f;
        }
        for (int k = 0; k < SUBCH; ++k) {
            const int cbase = superBase + k * CHUNK;
            if (cbase >= N) break;
            const int end = (cbase + CHUNK < N) ? cbase + CHUNK : N;
            float s = 0.f;
            for (int i = cbase + (int)threadIdx.x; i < end; i += BLK) {
                const float o = outs[i];
                const int e = te[i];
                int sg = tt[i]; sg = sg < 0 ? -sg : sg;
                s += __expf(o);
                if (e > 0) { cntE++; sumOE += o; atomicAdd(&hist[sg], 1u); }
            }
            const float w = waveReduceSumF(s);
            if (lane == 0) redC[k][wid] = w;
        }
    }

    // E-stat wave partials
    {
        const float wOE = waveReduceSumF(sumOE);
        const unsigned wC = waveReduceSumU(cntE);
        if (lane == 0) { redF[wid] = wOE; redU[wid] = wC; }
    }

    __syncthreads();  // hist + redC/redF/redU complete

    // hist -> per-block u16 partials (plain coalesced stores, no atomics)
    for (int t = threadIdx.x; t < NUM_SEGS; t += BLK)
        hist_part[(size_t)bid * NUM_SEGS + t] = (unsigned short)hist[t];

    if (threadIdx.x == 0) {
        const int c0 = superBase >> CHUNK_LOG;
#pragma unroll
        for (int k = 0; k < SUBCH; ++k) {
            const int cbase = superBase + k * CHUNK;
            if (cbase < N) {
                float cs = 0.f;
#pragma unroll
                for (int j = 0; j < NWAVE; ++j) cs += redC[k][j];
                csums[c0 + k] = cs;
            }
        }
        float oe = 0.f; unsigned c = 0u;
#pragma unroll
        for (int j = 0; j < NWAVE; ++j) { oe += redF[j]; c += redU[j]; }
        e1part[bid] = oe;
        obspart[bid] = c;
    }
}

// ---------------- pass 2: per-segment work + direct fp32 accumulation to out -
// (byte-identical logic to r10's passing version)
__global__ __launch_bounds__(SEGBLK) void seg_final_kernel(
    const float* __restrict__ outs, const int* __restrict__ tt,
    const float* __restrict__ csums, const unsigned short* __restrict__ hist_part,
    const float* __restrict__ e1part, const unsigned* __restrict__ obspart,
    float* __restrict__ out, int N, int nChunks, int nSuper) {
    __shared__ double redD[SEGWAVES];
    __shared__ float redF[SEGWAVES];
    __shared__ int redI[SEGWAVES];
    __shared__ unsigned redObs[SEGWAVES];
    __shared__ unsigned redCnt[SEGWAVES];
    __shared__ int s_li;
    __shared__ unsigned s_cnt;

    const int t = (int)blockIdx.x;
    const int tid = (int)threadIdx.x;
    const int lane = tid & 63, wid = tid >> 6;

    // Obs partial-sum (kept in redObs; only tid 0 consumes it later)
    {
        unsigned ob = 0u;
        for (int b = tid; b < nSuper; b += SEGBLK) ob += obspart[b];
        ob = waveReduceSumU(ob);
        if (lane == 0) redObs[wid] = ob;
    }

    // block 0: the -loss1/Obs term
    if (t == 0) {
        double p = 0.0;
        for (int b = tid; b < nSuper; b += SEGBLK) p += (double)e1part[b];
        p = waveReduceSumD(p);
        if (lane == 0) redD[wid] = p;
        __syncthreads();
        if (tid == 0) {
            double L1 = 0.0, Obs = 0.0;
#pragma unroll
            for (int j = 0; j < SEGWAVES; ++j) {
                L1 += redD[j];
                Obs += (double)redObs[j];
            }
            atomicAdd(out, (float)(-L1 / Obs));
        }
        __syncthreads();  // redD reused below
    }

    // cnt for this segment: column sum of u16 partials
    {
        unsigned c = 0u;
        for (int b = tid; b < nSuper; b += SEGBLK)
            c += (unsigned)hist_part[(size_t)b * NUM_SEGS + t];
        c = waveReduceSumU(c);
        if (lane == 0) redCnt[wid] = c;
    }
    __syncthreads();
    if (tid == 0) {
        unsigned c = 0u;
#pragma unroll
        for (int j = 0; j < SEGWAVES; ++j) c += redCnt[j];
        s_cnt = c;
    }
    __syncthreads();
    const unsigned cnt = s_cnt;
    if (cnt == 0u) return;  // empty segment contributes 0

    // ---- backward search for the last occurrence of segment t ----
    int c = nChunks - 1;
    int LI = -1;
    for (;;) {
        const int base = c << CHUNK_LOG;
        const int end = (base + CHUNK < N) ? base + CHUNK : N;
        const int span = end - base;
        const int qspan = span & ~3;  // int4-aligned portion
        int li = -1;
        for (int i = base + (tid << 2); i < base + qspan; i += SEGBLK * 4) {
            const int4 sv = *reinterpret_cast<const int4*>(tt + i);
            const int s0 = sv.x < 0 ? -sv.x : sv.x;
            const int s1 = sv.y < 0 ? -sv.y : sv.y;
            const int s2 = sv.z < 0 ? -sv.z : sv.z;
            const int s3 = sv.w < 0 ? -sv.w : sv.w;
            if (s3 == t) li = i + 3;
            else if (s2 == t) li = i + 2;
            else if (s1 == t) li = i + 1;
            else if (s0 == t) li = i;
            // ascending i => later assignment always larger
        }
        for (int i = base + qspan + tid; i < end; i += SEGBLK) {
            int s = tt[i]; s = s < 0 ? -s : s;
            if (s == t && i > li) li = i;
        }
        li = waveReduceMaxI(li);
        if (lane == 0) redI[wid] = li;
        __syncthreads();
        if (tid == 0) {
            int m = redI[0];
#pragma unroll
            for (int j = 1; j < SEGWAVES; ++j) m = redI[j] > m ? redI[j] : m;
            s_li = m;
        }
        __syncthreads();
        LI = s_li;
        if (LI >= 0 || --c < 0) break;
    }
    if (LI < 0) return;

    // fp64 exclusive prefix of chunk sums [0, c)
    {
        double p = 0.0;
        for (int j = tid; j < c; j += SEGBLK) p += (double)csums[j];
        p = waveReduceSumD(p);
        if (lane == 0) redD[wid] = p;
    }

    // fp32 in-chunk exp-sum up to and including LI
    {
        const int base = c << CHUNK_LOG;
        float fs = 0.f;
        for (int i = base + tid; i <= LI; i += SEGBLK) fs += __expf(outs[i]);
        fs = waveReduceSumF(fs);
        if (lane == 0) redF[wid] = fs;
    }
    __syncthreads();
    if (tid == 0) {
        double pre = 0.0, Obs = 0.0;
        float fsum = 0.f;
#pragma unroll
        for (int j = 0; j < SEGWAVES; ++j) {
            pre += redD[j];
            fsum += redF[j];
            Obs += (double)redObs[j];
        }
        double sm = log(pre + (double)fsum);  // monotone cumsum => max at LI
        if (sm < 0.0) sm = 0.0;               // jnp.maximum(..., 0.0)
        atomicAdd(out, (float)(sm * (double)cnt / Obs));
    }
}

extern "C" void kernel_launch(void* const* d_in, const int* in_sizes, int n_in,
                              void* d_out, int out_size, void* d_ws, size_t ws_size,
                              hipStream_t stream) {
    const float* outs = (const float*)d_in[0];
    const int* te = (const int*)d_in[1];
    const int* tt = (const int*)d_in[2];
    const int N = in_sizes[0];
    float* out = (float*)d_out;

    const int nChunks = (N + CHUNK - 1) / CHUNK;
    const int nSuper = (N + SUPER - 1) / SUPER;

    // workspace layout: everything is written by pass1 before seg_final reads
    // it -- no initialization dispatch, no poisoned-state hazard.
    char* ws = (char*)d_ws;
    float* d_csums = (float*)ws;                                   // nChunks f32
    unsigned short* d_histp = (unsigned short*)(d_csums + nChunks);  // nSuper*1024 u16
    float* d_e1 = (float*)(d_histp + (size_t)nSuper * NUM_SEGS);   // nSuper f32
    unsigned* d_obsp = (unsigned*)(d_e1 + nSuper);                 // nSuper u32

    pass1_kernel<<<nSuper, BLK, 0, stream>>>(outs, te, tt, N, nChunks, d_csums,
                                             d_histp, d_e1, d_obsp);
    seg_final_kernel<<<NUM_SEGS, SEGBLK, 0, stream>>>(
        outs, tt, d_csums, d_histp, d_e1, d_obsp, out, N, nChunks, nSuper);
}